// Round 3
// baseline (15966.209 us; speedup 1.0000x reference)
//
#include <hip/hip_runtime.h>

#define DI __device__ __forceinline__

typedef short s16x8 __attribute__((ext_vector_type(8)));
typedef float f32x4 __attribute__((ext_vector_type(4)));

constexpr int CB = 64, CL = 512, CV = 256, CE = 512, CH = 1024;
constexpr int CBL = CB * CL;                // 32768
constexpr size_t LOGN = (size_t)CBL * CV;   // 8388608 floats of logits

// ---- workspace layout (bytes) ----
constexpr size_t WS_BAR   = 0;                              // flags: 16 ints (one line)
constexpr size_t WS_H     = 4096;                           // h ping-pong 2*64*1024*2 = 256 KiB
constexpr size_t WS_EMBB  = WS_H    + 2u*CB*CH*2;           // emb bf16   256*512*2
constexpr size_t WS_UWB   = WS_EMBB + (size_t)CV*CE*2;      // U_w bf16   1024*512*2
constexpr size_t WS_VWB   = WS_UWB  + (size_t)CH*CE*2;      // V_w bf16   1024*1024*2
constexpr size_t WS_DECWB = WS_VWB  + (size_t)CH*CH*2;      // dec_w bf16 256*1024*2
constexpr size_t WS_UX    = WS_DECWB+ (size_t)CV*CH*2;      // Ux bf16    32768*1024*2
constexpr size_t WS_HS    = WS_UX   + (size_t)CBL*CH*2;     // hs bf16    32768*1024*2

DI unsigned short f2bf(float f) {            // RNE f32 -> bf16
  unsigned u = __float_as_uint(f);
  u += 0x7FFFu + ((u >> 16) & 1u);
  return (unsigned short)(u >> 16);
}
DI float bf2f(unsigned short h) { return __uint_as_float(((unsigned)h) << 16); }

DI f32x4 mfma_bf16(s16x8 a, s16x8 b, f32x4 c) {
  return __builtin_amdgcn_mfma_f32_16x16x32_bf16(a, b, c, 0, 0, 0);
}

DI float fast_tanh(float x) {
  float a = fminf(fabsf(x), 20.0f);
  float e = __expf(-2.0f * a);
  float r = (1.0f - e) / (1.0f + e);
  return __builtin_copysignf(r, x);
}

// ---------------- convert f32 weights -> bf16 in ws ----------------
__global__ __launch_bounds__(256) void k_convert(
    const float* __restrict__ emb, const float* __restrict__ uw,
    const float* __restrict__ vw,  const float* __restrict__ dw,
    unsigned short* __restrict__ embb, unsigned short* __restrict__ uwb,
    unsigned short* __restrict__ vwb,  unsigned short* __restrict__ dwb)
{
  int i = (blockIdx.x * 256 + threadIdx.x) * 4;   // 1966080 elems total, grid exact
  const float* s; unsigned short* d; int off;
  if      (i < 131072)  { s = emb; d = embb; off = i; }
  else if (i < 655360)  { s = uw;  d = uwb;  off = i - 131072; }
  else if (i < 1703936) { s = vw;  d = vwb;  off = i - 655360; }
  else                  { s = dw;  d = dwb;  off = i - 1703936; }
  float4 v = *(const float4*)(s + off);
  ushort4 o; o.x = f2bf(v.x); o.y = f2bf(v.y); o.z = f2bf(v.z); o.w = f2bf(v.w);
  *(ushort4*)(d + off) = o;
}

// ---------------- generic bf16 MFMA GEMM: C[r, n] = sum_k A[r,k]*B[n,k] ----------------
template<int KD, int NT, bool GATHER, bool OUTF32>
__global__ __launch_bounds__(256) void k_gemm(
    const unsigned short* __restrict__ Asrc,
    const int* __restrict__ xidx,
    const unsigned short* __restrict__ Bsrc,
    const float* __restrict__ biasv,
    unsigned short* __restrict__ Cb,
    float* __restrict__ Cf)
{
  __shared__ unsigned char As[64 * 128];
  __shared__ unsigned char Bs[64 * 128];
  __shared__ int xs[64];

  const int tid = threadIdx.x;
  const int rt = blockIdx.x, ct = blockIdx.y;
  const int r0 = rt * 64, c0 = ct * 64;

  if (GATHER) {
    if (tid < 64) xs[tid] = xidx[r0 + tid];
    __syncthreads();
  }

  const int r  = tid >> 2, kq = tid & 3;
  const unsigned short* aRow = GATHER ? (Asrc + (size_t)xs[r] * KD)
                                      : (Asrc + (size_t)(r0 + r) * KD);
  const unsigned short* bRow = Bsrc + (size_t)(c0 + r) * KD;
  const int dstOff = r * 128 + ((kq * 16) ^ ((r & 7) << 4));

  const int wave = tid >> 6, lane = tid & 63;
  const int ln15 = lane & 15, lg = lane >> 4;
  const int xr = (lane & 7) << 4;
  int aOff[4];
#pragma unroll
  for (int m = 0; m < 4; ++m) aOff[m] = (m * 16 + ln15) * 128 + ((lg * 16) ^ xr);
  const int bOff = (wave * 16 + ln15) * 128 + ((lg * 16) ^ xr);

  f32x4 acc[4] = {};
  for (int kk = 0; kk < KD / 32; ++kk) {
    s16x8 av = *(const s16x8*)(aRow + kk * 32 + kq * 8);
    s16x8 bv = *(const s16x8*)(bRow + kk * 32 + kq * 8);
    __syncthreads();
    *(s16x8*)(As + dstOff) = av;
    *(s16x8*)(Bs + dstOff) = bv;
    __syncthreads();
    s16x8 bf = *(const s16x8*)(Bs + bOff);
#pragma unroll
    for (int m = 0; m < 4; ++m) {
      s16x8 af = *(const s16x8*)(As + aOff[m]);
      acc[m] = mfma_bf16(af, bf, acc[m]);
    }
  }

  const int colg = c0 + wave * 16 + ln15;
  float bv = 0.f;
  if (OUTF32) bv = biasv[colg];
#pragma unroll
  for (int m = 0; m < 4; ++m) {
#pragma unroll
    for (int rr = 0; rr < 4; ++rr) {
      int rowg = r0 + m * 16 + lg * 4 + rr;
      if (OUTF32) Cf[(size_t)rowg * NT + colg] = acc[m][rr] + bv;
      else        Cb[(size_t)rowg * NT + colg] = f2bf(acc[m][rr]);
    }
  }
}

// ---------------- persistent recurrence, v2 ----------------
// 16 wgs x 256 thr. wg w owns cols w*64..w*64+63 for ALL 64 batches.
// Each wave holds V_w slice [16 cols x 1024 K] in 128 VGPRs forever.
// Cross-wg h exchange via sc0sc1 (L2-bypass, L3-coherent) accesses ONLY —
// no wbl2/inv fences. Barrier: per-wg flag slot (one cache line total),
// publish = relaxed system atomic store after vmcnt(0); wait = 16-lane
// vector atomic poll.
__global__ __launch_bounds__(256, 1) void k_rec(
    const unsigned short* __restrict__ vwb,   // [H][H] bf16
    const unsigned short* __restrict__ ux,    // [B][L][H] bf16
    unsigned short* __restrict__ hping,       // [2][B][H] bf16
    unsigned short* __restrict__ hs,          // [B][L][H] bf16
    const float* __restrict__ alpha, const float* __restrict__ beta1,
    const float* __restrict__ beta2, const float* __restrict__ bias,
    float* __restrict__ out, int* flags)
{
  const int w = blockIdx.x;                 // col-slice 0..15
  const int tid = threadIdx.x;
  const int wave = tid >> 6, lane = tid & 63;
  const int ln15 = lane & 15, lg = lane >> 4;
  const int mycol = w * 64 + wave * 16 + ln15;

  // B-operand resident: breg[kc] lane l = V_w[mycol][kc*32 + (l>>4)*8 ..+8]
  s16x8 breg[32];
  {
    const unsigned short* vrow = vwb + (size_t)mycol * CH + lg * 8;
#pragma unroll
    for (int kc = 0; kc < 32; ++kc) breg[kc] = *(const s16x8*)(vrow + kc * 32);
  }
  const float al = alpha[mycol], b1 = beta1[mycol], b2 = beta2[mycol], bi = bias[mycol];

  // Buffer descriptor over the 256 KiB hping region; loads use aux=17
  // (SC0|SC1, gfx940+ CPol): bypass L1/L2, served coherently at L3.
  __amdgpu_buffer_rsrc_t hsrd = __builtin_amdgcn_make_buffer_rsrc(
      (void*)hping, (short)0, (int)(2u * CB * CH * 2), 0x00020000);

  // per-lane A-frag base offsets (bytes): row (m*16+ln15), k chunk lg*8
  unsigned aBase[4];
#pragma unroll
  for (int m = 0; m < 4; ++m)
    aBase[m] = (unsigned)(((m * 16 + ln15) * CH + lg * 8) * 2);

  unsigned short uxr[16];
#pragma unroll
  for (int m = 0; m < 4; ++m)
#pragma unroll
    for (int rr = 0; rr < 4; ++rr) {
      int b = m * 16 + lg * 4 + rr;
      uxr[m * 4 + rr] = ux[((size_t)b * CL + 0) * CH + mycol];
    }

  for (int t = 0; t < CL; ++t) {
    f32x4 acc[4] = {};
    if (t > 0) {
      const unsigned roff = (t & 1) ? (unsigned)(CB * CH * 2) : 0u;
#pragma unroll
      for (int kc = 0; kc < 32; ++kc) {
#pragma unroll
        for (int m = 0; m < 4; ++m) {
          auto raw = __builtin_amdgcn_raw_buffer_load_b128(
              hsrd, (int)(roff + aBase[m] + kc * 64), 0, /*sc0|sc1*/ 17);
          s16x8 a = __builtin_bit_cast(s16x8, raw);
          acc[m] = mfma_bf16(a, breg[kc], acc[m]);
        }
      }
    }

    // pointwise + stores
    unsigned short* hnext = hping + (size_t)((t + 1) & 1) * (CB * CH);
#pragma unroll
    for (int m = 0; m < 4; ++m) {
#pragma unroll
      for (int rr = 0; rr < 4; ++rr) {
        const int b = m * 16 + lg * 4 + rr;
        const float u = bf2f(uxr[m * 4 + rr]);
        const float v = acc[m][rr];
        const float mm = al * (v * u) + b1 * v + b2 * u + bi;
        const float hn = fast_tanh(mm);
        const unsigned short hb = f2bf(hn);
        // h exchange: write-through to L3 (sc0 sc1) via system-scope relaxed atomic
        __hip_atomic_store(hnext + b * CH + mycol, hb,
                           __ATOMIC_RELAXED, __HIP_MEMORY_SCOPE_SYSTEM);
        hs[((size_t)b * CL + t) * CH + mycol] = hb;      // normal cached store
        if (t == CL - 1) out[LOGN + (size_t)b * CH + mycol] = hn;
      }
    }

    if (t < CL - 1) {
      // release: drain h stores to the coherence point
      asm volatile("s_waitcnt vmcnt(0)" ::: "memory");
      // prefetch next step's ux during the rendezvous (normal cached loads)
      unsigned short uxn[16];
#pragma unroll
      for (int m = 0; m < 4; ++m)
#pragma unroll
        for (int rr = 0; rr < 4; ++rr) {
          int b = m * 16 + lg * 4 + rr;
          uxn[m * 4 + rr] = ux[((size_t)b * CL + (t + 1)) * CH + mycol];
        }
      __syncthreads();                     // all 4 waves drained
      if (tid == 0)
        __hip_atomic_store(&flags[w], t + 1, __ATOMIC_RELAXED, __HIP_MEMORY_SCOPE_SYSTEM);
      // all waves poll independently (no second barrier needed)
      const int target = t + 1;
      bool ok;
      do {
        int fv = (lane < 16)
                     ? __hip_atomic_load(&flags[lane], __ATOMIC_RELAXED, __HIP_MEMORY_SCOPE_SYSTEM)
                     : target;
        ok = __all(fv >= target) != 0;
        if (!ok) __builtin_amdgcn_s_sleep(1);
      } while (!ok);
      asm volatile("" ::: "memory");       // compiler: no hoisting of h loads above poll
#pragma unroll
      for (int i = 0; i < 16; ++i) uxr[i] = uxn[i];
    }
  }
}

extern "C" void kernel_launch(void* const* d_in, const int* in_sizes, int n_in,
                              void* d_out, int out_size, void* d_ws, size_t ws_size,
                              hipStream_t stream) {
  const int*   x     = (const int*)  d_in[0];
  const float* emb   = (const float*)d_in[1];
  const float* Uw    = (const float*)d_in[2];
  const float* Vw    = (const float*)d_in[3];
  const float* alpha = (const float*)d_in[4];
  const float* beta1 = (const float*)d_in[5];
  const float* beta2 = (const float*)d_in[6];
  const float* bias  = (const float*)d_in[7];
  const float* decw  = (const float*)d_in[8];
  const float* decb  = (const float*)d_in[9];
  float* out = (float*)d_out;
  char*  ws  = (char*)d_ws;

  int*            flags = (int*)(ws + WS_BAR);
  unsigned short* hping = (unsigned short*)(ws + WS_H);
  unsigned short* embb  = (unsigned short*)(ws + WS_EMBB);
  unsigned short* uwb   = (unsigned short*)(ws + WS_UWB);
  unsigned short* vwb   = (unsigned short*)(ws + WS_VWB);
  unsigned short* dwb   = (unsigned short*)(ws + WS_DECWB);
  unsigned short* uxb   = (unsigned short*)(ws + WS_UX);
  unsigned short* hsb   = (unsigned short*)(ws + WS_HS);

  (void)hipMemsetAsync(ws + WS_BAR, 0, 4096, stream);   // reset flags every call

  k_convert<<<1920, 256, 0, stream>>>(emb, Uw, Vw, decw, embb, uwb, vwb, dwb);

  k_gemm<CE, CH, true, false><<<dim3(CBL / 64, CH / 64), 256, 0, stream>>>(
      embb, x, uwb, nullptr, uxb, nullptr);

  k_rec<<<16, 256, 0, stream>>>(vwb, uxb, hping, hsb, alpha, beta1, beta2, bias, out, flags);

  k_gemm<CH, CV, false, true><<<dim3(CBL / 64, CV / 64), 256, 0, stream>>>(
      hsb, nullptr, dwb, decb, nullptr, out);
}

// Round 4
// 3642.401 us; speedup vs baseline: 4.3834x; 4.3834x over previous
//
#include <hip/hip_runtime.h>

#define DI __device__ __forceinline__

typedef short s16x8 __attribute__((ext_vector_type(8)));
typedef float f32x4 __attribute__((ext_vector_type(4)));

constexpr int CB = 64, CL = 512, CV = 256, CE = 512, CH = 1024;
constexpr int CBL = CB * CL;                // 32768
constexpr size_t LOGN = (size_t)CBL * CV;   // 8388608 floats of logits

// ---- workspace layout (bytes) ----
constexpr size_t WS_BAR   = 0;                              // flags: 4 groups x 64 ints
constexpr size_t WS_H     = 4096;                           // h ping-pong 2*64*1024*2 = 256 KiB
constexpr size_t WS_EMBB  = WS_H    + 2u*CB*CH*2;           // emb bf16   256*512*2
constexpr size_t WS_UWB   = WS_EMBB + (size_t)CV*CE*2;      // U_w bf16   1024*512*2
constexpr size_t WS_VWB   = WS_UWB  + (size_t)CH*CE*2;      // V_w bf16   1024*1024*2
constexpr size_t WS_DECWB = WS_VWB  + (size_t)CH*CH*2;      // dec_w bf16 256*1024*2
constexpr size_t WS_UX    = WS_DECWB+ (size_t)CV*CH*2;      // Ux bf16    32768*1024*2
constexpr size_t WS_HS    = WS_UX   + (size_t)CBL*CH*2;     // hs bf16    32768*1024*2

DI unsigned short f2bf(float f) {            // RNE f32 -> bf16
  unsigned u = __float_as_uint(f);
  u += 0x7FFFu + ((u >> 16) & 1u);
  return (unsigned short)(u >> 16);
}
DI float bf2f(unsigned short h) { return __uint_as_float(((unsigned)h) << 16); }

DI f32x4 mfma_bf16(s16x8 a, s16x8 b, f32x4 c) {
  return __builtin_amdgcn_mfma_f32_16x16x32_bf16(a, b, c, 0, 0, 0);
}

DI float fast_tanh(float x) {
  float a = fminf(fabsf(x), 20.0f);
  float e = __expf(-2.0f * a);
  float r = (1.0f - e) / (1.0f + e);
  return __builtin_copysignf(r, x);
}

// ---------------- convert f32 weights -> bf16 in ws ----------------
__global__ __launch_bounds__(256) void k_convert(
    const float* __restrict__ emb, const float* __restrict__ uw,
    const float* __restrict__ vw,  const float* __restrict__ dw,
    unsigned short* __restrict__ embb, unsigned short* __restrict__ uwb,
    unsigned short* __restrict__ vwb,  unsigned short* __restrict__ dwb)
{
  int i = (blockIdx.x * 256 + threadIdx.x) * 4;   // 1966080 elems total, grid exact
  const float* s; unsigned short* d; int off;
  if      (i < 131072)  { s = emb; d = embb; off = i; }
  else if (i < 655360)  { s = uw;  d = uwb;  off = i - 131072; }
  else if (i < 1703936) { s = vw;  d = vwb;  off = i - 655360; }
  else                  { s = dw;  d = dwb;  off = i - 1703936; }
  float4 v = *(const float4*)(s + off);
  ushort4 o; o.x = f2bf(v.x); o.y = f2bf(v.y); o.z = f2bf(v.z); o.w = f2bf(v.w);
  *(ushort4*)(d + off) = o;
}

// ---------------- generic bf16 MFMA GEMM: C[r, n] = sum_k A[r,k]*B[n,k] ----------------
template<int KD, int NT, bool GATHER, bool OUTF32>
__global__ __launch_bounds__(256) void k_gemm(
    const unsigned short* __restrict__ Asrc,
    const int* __restrict__ xidx,
    const unsigned short* __restrict__ Bsrc,
    const float* __restrict__ biasv,
    unsigned short* __restrict__ Cb,
    float* __restrict__ Cf)
{
  __shared__ unsigned char As[64 * 128];
  __shared__ unsigned char Bs[64 * 128];
  __shared__ int xs[64];

  const int tid = threadIdx.x;
  const int rt = blockIdx.x, ct = blockIdx.y;
  const int r0 = rt * 64, c0 = ct * 64;

  if (GATHER) {
    if (tid < 64) xs[tid] = xidx[r0 + tid];
    __syncthreads();
  }

  const int r  = tid >> 2, kq = tid & 3;
  const unsigned short* aRow = GATHER ? (Asrc + (size_t)xs[r] * KD)
                                      : (Asrc + (size_t)(r0 + r) * KD);
  const unsigned short* bRow = Bsrc + (size_t)(c0 + r) * KD;
  const int dstOff = r * 128 + ((kq * 16) ^ ((r & 7) << 4));

  const int wave = tid >> 6, lane = tid & 63;
  const int ln15 = lane & 15, lg = lane >> 4;
  const int xr = (lane & 7) << 4;
  int aOff[4];
#pragma unroll
  for (int m = 0; m < 4; ++m) aOff[m] = (m * 16 + ln15) * 128 + ((lg * 16) ^ xr);
  const int bOff = (wave * 16 + ln15) * 128 + ((lg * 16) ^ xr);

  f32x4 acc[4] = {};
  for (int kk = 0; kk < KD / 32; ++kk) {
    s16x8 av = *(const s16x8*)(aRow + kk * 32 + kq * 8);
    s16x8 bv = *(const s16x8*)(bRow + kk * 32 + kq * 8);
    __syncthreads();
    *(s16x8*)(As + dstOff) = av;
    *(s16x8*)(Bs + dstOff) = bv;
    __syncthreads();
    s16x8 bf = *(const s16x8*)(Bs + bOff);
#pragma unroll
    for (int m = 0; m < 4; ++m) {
      s16x8 af = *(const s16x8*)(As + aOff[m]);
      acc[m] = mfma_bf16(af, bf, acc[m]);
    }
  }

  const int colg = c0 + wave * 16 + ln15;
  float bv = 0.f;
  if (OUTF32) bv = biasv[colg];
#pragma unroll
  for (int m = 0; m < 4; ++m) {
#pragma unroll
    for (int rr = 0; rr < 4; ++rr) {
      int rowg = r0 + m * 16 + lg * 4 + rr;
      if (OUTF32) Cf[(size_t)rowg * NT + colg] = acc[m][rr] + bv;
      else        Cb[(size_t)rowg * NT + colg] = f2bf(acc[m][rr]);
    }
  }
}

// ---------------- persistent recurrence, v3 ----------------
// 64 wgs x 256 thr = R1 geometry. wg=(bg,cs): batches bg*16..+16, cols cs*64..+64.
// Each wave holds V_w slice [16 cols x 1024 K] in 128 VGPRs forever; each wave
// loads only its group's 16-batch h slice (32 b128 sc0sc1 loads/lane).
// Sync = R2's proven fence-free protocol, per group of 16 wgs:
//   vmcnt(0) drain -> slot-flag store (sc0sc1) -> 16-lane vector poll.
__global__ __launch_bounds__(256, 1) void k_rec(
    const unsigned short* __restrict__ vwb,   // [H][H] bf16
    const unsigned short* __restrict__ ux,    // [B][L][H] bf16
    unsigned short* __restrict__ hping,       // [2][B][H] bf16
    unsigned short* __restrict__ hs,          // [B][L][H] bf16
    const float* __restrict__ alpha, const float* __restrict__ beta1,
    const float* __restrict__ beta2, const float* __restrict__ bias,
    float* __restrict__ out, int* flags)
{
  const int w = blockIdx.x;
  const int bg = w >> 4, cs = w & 15;       // batch-group, col-slice
  const int tid = threadIdx.x;
  const int wave = tid >> 6, lane = tid & 63;
  const int ln15 = lane & 15, lg = lane >> 4;
  const int b0 = bg * 16;
  const int mycol = cs * 64 + wave * 16 + ln15;

  // B-operand resident: breg[kc] lane l = V_w[mycol][kc*32 + (l>>4)*8 ..+8]
  s16x8 breg[32];
  {
    const unsigned short* vrow = vwb + (size_t)mycol * CH + lg * 8;
#pragma unroll
    for (int kc = 0; kc < 32; ++kc) breg[kc] = *(const s16x8*)(vrow + kc * 32);
  }
  const float al = alpha[mycol], b1 = beta1[mycol], b2 = beta2[mycol], bi = bias[mycol];

  // Buffer descriptor over hping (256 KiB); h loads use aux=17 (SC0|SC1):
  // bypass L1/L2, served coherently at L3. Protocol validated in R2.
  __amdgpu_buffer_rsrc_t hsrd = __builtin_amdgcn_make_buffer_rsrc(
      (void*)hping, (short)0, (int)(2u * CB * CH * 2), 0x00020000);

  // A-frag base (bytes): row = b0+ln15 (batch), k-chunk lg*8
  const unsigned aBase = (unsigned)((((b0 + ln15) * CH) + lg * 8) * 2);

  int* gflags = flags + bg * 64;            // one 64B line per group

  unsigned short uxr[4];
#pragma unroll
  for (int rr = 0; rr < 4; ++rr) {
    int b = b0 + lg * 4 + rr;
    uxr[rr] = ux[((size_t)b * CL + 0) * CH + mycol];
  }

  for (int t = 0; t < CL; ++t) {
    f32x4 vh = {};
    if (t > 0) {
      const unsigned roff = (t & 1) ? (unsigned)(CB * CH * 2) : 0u;
      f32x4 a0 = {}, a1 = {};               // two chains to break MFMA dep latency
#pragma unroll
      for (int kc = 0; kc < 32; kc += 2) {
        auto r0 = __builtin_amdgcn_raw_buffer_load_b128(
            hsrd, (int)(roff + aBase + kc * 64), 0, 17);
        auto r1 = __builtin_amdgcn_raw_buffer_load_b128(
            hsrd, (int)(roff + aBase + kc * 64 + 64), 0, 17);
        a0 = mfma_bf16(__builtin_bit_cast(s16x8, r0), breg[kc],     a0);
        a1 = mfma_bf16(__builtin_bit_cast(s16x8, r1), breg[kc + 1], a1);
      }
      vh = a0 + a1;
    }

    unsigned short* hnext = hping + (size_t)((t + 1) & 1) * (CB * CH);
#pragma unroll
    for (int rr = 0; rr < 4; ++rr) {
      const int b = b0 + lg * 4 + rr;
      const float u = bf2f(uxr[rr]);
      const float v = vh[rr];
      const float mm = al * (v * u) + b1 * v + b2 * u + bi;
      const float hn = fast_tanh(mm);
      const unsigned short hb = f2bf(hn);
      // h exchange: write-through to L3 (sc0 sc1), no fence
      __hip_atomic_store(hnext + b * CH + mycol, hb,
                         __ATOMIC_RELAXED, __HIP_MEMORY_SCOPE_SYSTEM);
      hs[((size_t)b * CL + t) * CH + mycol] = hb;      // normal cached store
      if (t == CL - 1) out[LOGN + (size_t)b * CH + mycol] = hn;
    }

    if (t < CL - 1) {
      // prefetch next ux (overlaps with store drain)
      unsigned short uxn[4];
#pragma unroll
      for (int rr = 0; rr < 4; ++rr) {
        int b = b0 + lg * 4 + rr;
        uxn[rr] = ux[((size_t)b * CL + (t + 1)) * CH + mycol];
      }
      // release: drain h stores to the coherence point
      asm volatile("s_waitcnt vmcnt(0)" ::: "memory");
      __syncthreads();                      // all 4 waves drained
      if (tid == 0)
        __hip_atomic_store(&gflags[cs], t + 1, __ATOMIC_RELAXED, __HIP_MEMORY_SCOPE_SYSTEM);
      // all waves poll their group's flag line independently
      const int target = t + 1;
      bool ok;
      do {
        int fv = (lane < 16)
                     ? __hip_atomic_load(&gflags[lane], __ATOMIC_RELAXED, __HIP_MEMORY_SCOPE_SYSTEM)
                     : target;
        ok = __all(fv >= target) != 0;
        if (!ok) __builtin_amdgcn_s_sleep(1);
      } while (!ok);
      asm volatile("" ::: "memory");        // no hoisting of h loads above poll
#pragma unroll
      for (int rr = 0; rr < 4; ++rr) uxr[rr] = uxn[rr];
    }
  }
}

extern "C" void kernel_launch(void* const* d_in, const int* in_sizes, int n_in,
                              void* d_out, int out_size, void* d_ws, size_t ws_size,
                              hipStream_t stream) {
  const int*   x     = (const int*)  d_in[0];
  const float* emb   = (const float*)d_in[1];
  const float* Uw    = (const float*)d_in[2];
  const float* Vw    = (const float*)d_in[3];
  const float* alpha = (const float*)d_in[4];
  const float* beta1 = (const float*)d_in[5];
  const float* beta2 = (const float*)d_in[6];
  const float* bias  = (const float*)d_in[7];
  const float* decw  = (const float*)d_in[8];
  const float* decb  = (const float*)d_in[9];
  float* out = (float*)d_out;
  char*  ws  = (char*)d_ws;

  int*            flags = (int*)(ws + WS_BAR);
  unsigned short* hping = (unsigned short*)(ws + WS_H);
  unsigned short* embb  = (unsigned short*)(ws + WS_EMBB);
  unsigned short* uwb   = (unsigned short*)(ws + WS_UWB);
  unsigned short* vwb   = (unsigned short*)(ws + WS_VWB);
  unsigned short* dwb   = (unsigned short*)(ws + WS_DECWB);
  unsigned short* uxb   = (unsigned short*)(ws + WS_UX);
  unsigned short* hsb   = (unsigned short*)(ws + WS_HS);

  (void)hipMemsetAsync(ws + WS_BAR, 0, 4096, stream);   // reset flags every call

  k_convert<<<1920, 256, 0, stream>>>(emb, Uw, Vw, decw, embb, uwb, vwb, dwb);

  k_gemm<CE, CH, true, false><<<dim3(CBL / 64, CH / 64), 256, 0, stream>>>(
      embb, x, uwb, nullptr, uxb, nullptr);

  k_rec<<<64, 256, 0, stream>>>(vwb, uxb, hping, hsb, alpha, beta1, beta2, bias, out, flags);

  k_gemm<CH, CV, false, true><<<dim3(CBL / 64, CV / 64), 256, 0, stream>>>(
      hsb, nullptr, dwb, decb, nullptr, out);
}

// Round 5
// 3624.979 us; speedup vs baseline: 4.4045x; 1.0048x over previous
//
#include <hip/hip_runtime.h>

#define DI __device__ __forceinline__

typedef short s16x8 __attribute__((ext_vector_type(8)));
typedef float f32x4 __attribute__((ext_vector_type(4)));

constexpr int CB = 64, CL = 512, CV = 256, CE = 512, CH = 1024;
constexpr int CBL = CB * CL;                // 32768
constexpr size_t LOGN = (size_t)CBL * CV;   // 8388608 floats of logits

// ---- workspace layout (bytes) ----
constexpr size_t WS_BAR   = 0;                              // flags: 4 groups x 64 ints
constexpr size_t WS_H     = 4096;                           // h ping-pong 2*64*1024*2 = 256 KiB
constexpr size_t WS_EMBB  = WS_H    + 2u*CB*CH*2;           // emb bf16   256*512*2
constexpr size_t WS_UWB   = WS_EMBB + (size_t)CV*CE*2;      // U_w bf16   1024*512*2
constexpr size_t WS_VWB   = WS_UWB  + (size_t)CH*CE*2;      // V_w bf16   1024*1024*2
constexpr size_t WS_DECWB = WS_VWB  + (size_t)CH*CH*2;      // dec_w bf16 256*1024*2
constexpr size_t WS_UX    = WS_DECWB+ (size_t)CV*CH*2;      // Ux bf16    32768*1024*2
constexpr size_t WS_HS    = WS_UX   + (size_t)CBL*CH*2;     // hs bf16    32768*1024*2

DI unsigned short f2bf(float f) {            // RNE f32 -> bf16
  unsigned u = __float_as_uint(f);
  u += 0x7FFFu + ((u >> 16) & 1u);
  return (unsigned short)(u >> 16);
}
DI float bf2f(unsigned short h) { return __uint_as_float(((unsigned)h) << 16); }

DI f32x4 mfma_bf16(s16x8 a, s16x8 b, f32x4 c) {
  return __builtin_amdgcn_mfma_f32_16x16x32_bf16(a, b, c, 0, 0, 0);
}

DI float fast_tanh(float x) {
  float a = fminf(fabsf(x), 20.0f);
  float e = __expf(-2.0f * a);
  float r = (1.0f - e) / (1.0f + e);
  return __builtin_copysignf(r, x);
}

// ---------------- convert f32 weights -> bf16 in ws ----------------
__global__ __launch_bounds__(256) void k_convert(
    const float* __restrict__ emb, const float* __restrict__ uw,
    const float* __restrict__ vw,  const float* __restrict__ dw,
    unsigned short* __restrict__ embb, unsigned short* __restrict__ uwb,
    unsigned short* __restrict__ vwb,  unsigned short* __restrict__ dwb)
{
  int i = (blockIdx.x * 256 + threadIdx.x) * 4;   // 1966080 elems total, grid exact
  const float* s; unsigned short* d; int off;
  if      (i < 131072)  { s = emb; d = embb; off = i; }
  else if (i < 655360)  { s = uw;  d = uwb;  off = i - 131072; }
  else if (i < 1703936) { s = vw;  d = vwb;  off = i - 655360; }
  else                  { s = dw;  d = dwb;  off = i - 1703936; }
  float4 v = *(const float4*)(s + off);
  ushort4 o; o.x = f2bf(v.x); o.y = f2bf(v.y); o.z = f2bf(v.z); o.w = f2bf(v.w);
  *(ushort4*)(d + off) = o;
}

// ---------------- generic bf16 MFMA GEMM: C[r, n] = sum_k A[r,k]*B[n,k] ----------------
template<int KD, int NT, bool GATHER, bool OUTF32>
__global__ __launch_bounds__(256) void k_gemm(
    const unsigned short* __restrict__ Asrc,
    const int* __restrict__ xidx,
    const unsigned short* __restrict__ Bsrc,
    const float* __restrict__ biasv,
    unsigned short* __restrict__ Cb,
    float* __restrict__ Cf)
{
  __shared__ unsigned char As[64 * 128];
  __shared__ unsigned char Bs[64 * 128];
  __shared__ int xs[64];

  const int tid = threadIdx.x;
  const int rt = blockIdx.x, ct = blockIdx.y;
  const int r0 = rt * 64, c0 = ct * 64;

  if (GATHER) {
    if (tid < 64) xs[tid] = xidx[r0 + tid];
    __syncthreads();
  }

  const int r  = tid >> 2, kq = tid & 3;
  const unsigned short* aRow = GATHER ? (Asrc + (size_t)xs[r] * KD)
                                      : (Asrc + (size_t)(r0 + r) * KD);
  const unsigned short* bRow = Bsrc + (size_t)(c0 + r) * KD;
  const int dstOff = r * 128 + ((kq * 16) ^ ((r & 7) << 4));

  const int wave = tid >> 6, lane = tid & 63;
  const int ln15 = lane & 15, lg = lane >> 4;
  const int xr = (lane & 7) << 4;
  int aOff[4];
#pragma unroll
  for (int m = 0; m < 4; ++m) aOff[m] = (m * 16 + ln15) * 128 + ((lg * 16) ^ xr);
  const int bOff = (wave * 16 + ln15) * 128 + ((lg * 16) ^ xr);

  f32x4 acc[4] = {};
  for (int kk = 0; kk < KD / 32; ++kk) {
    s16x8 av = *(const s16x8*)(aRow + kk * 32 + kq * 8);
    s16x8 bv = *(const s16x8*)(bRow + kk * 32 + kq * 8);
    __syncthreads();
    *(s16x8*)(As + dstOff) = av;
    *(s16x8*)(Bs + dstOff) = bv;
    __syncthreads();
    s16x8 bf = *(const s16x8*)(Bs + bOff);
#pragma unroll
    for (int m = 0; m < 4; ++m) {
      s16x8 af = *(const s16x8*)(As + aOff[m]);
      acc[m] = mfma_bf16(af, bf, acc[m]);
    }
  }

  const int colg = c0 + wave * 16 + ln15;
  float bv = 0.f;
  if (OUTF32) bv = biasv[colg];
#pragma unroll
  for (int m = 0; m < 4; ++m) {
#pragma unroll
    for (int rr = 0; rr < 4; ++rr) {
      int rowg = r0 + m * 16 + lg * 4 + rr;
      if (OUTF32) Cf[(size_t)rowg * NT + colg] = acc[m][rr] + bv;
      else        Cb[(size_t)rowg * NT + colg] = f2bf(acc[m][rr]);
    }
  }
}

// ---------------- persistent recurrence, v4 ----------------
// 64 wgs x 256 thr (R3 geometry). wg=(bg,cs): batches bg*16..+16, cols cs*64..+64.
// V_w slice resident in 128 VGPRs/wave; h exchange sc0sc1 (L3-coherent), no fences.
// v4 barrier window (critical path = hnext-drain -> flag -> poll only):
//   hnext stores -> vmcnt(0) -> sync -> tid0 flag -> [hs stores + ux prefetch
//   overlap poll] -> wave0-only poll -> sync.
__global__ __launch_bounds__(256, 1) void k_rec(
    const unsigned short* __restrict__ vwb,   // [H][H] bf16
    const unsigned short* __restrict__ ux,    // [B][L][H] bf16
    unsigned short* __restrict__ hping,       // [2][B][H] bf16
    unsigned short* __restrict__ hs,          // [B][L][H] bf16
    const float* __restrict__ alpha, const float* __restrict__ beta1,
    const float* __restrict__ beta2, const float* __restrict__ bias,
    float* __restrict__ out, int* flags)
{
  const int w = blockIdx.x;
  const int bg = w >> 4, cs = w & 15;       // batch-group, col-slice
  const int tid = threadIdx.x;
  const int wave = tid >> 6, lane = tid & 63;
  const int ln15 = lane & 15, lg = lane >> 4;
  const int b0 = bg * 16;
  const int mycol = cs * 64 + wave * 16 + ln15;

  // B-operand resident: breg[kc] lane l = V_w[mycol][kc*32 + (l>>4)*8 ..+8]
  s16x8 breg[32];
  {
    const unsigned short* vrow = vwb + (size_t)mycol * CH + lg * 8;
#pragma unroll
    for (int kc = 0; kc < 32; ++kc) breg[kc] = *(const s16x8*)(vrow + kc * 32);
  }
  const float al = alpha[mycol], b1 = beta1[mycol], b2 = beta2[mycol], bi = bias[mycol];

  // h loads: aux=17 (SC0|SC1) — bypass L1/L2, coherent at L3. Proven in R2/R3.
  __amdgpu_buffer_rsrc_t hsrd = __builtin_amdgcn_make_buffer_rsrc(
      (void*)hping, (short)0, (int)(2u * CB * CH * 2), 0x00020000);

  // A-frag base (bytes): row = b0+ln15 (batch), k-chunk lg*8
  const unsigned aBase = (unsigned)((((b0 + ln15) * CH) + lg * 8) * 2);

  int* gflags = flags + bg * 64;            // one 64B line per group

  unsigned short uxr[4];
#pragma unroll
  for (int rr = 0; rr < 4; ++rr) {
    int b = b0 + lg * 4 + rr;
    uxr[rr] = ux[((size_t)b * CL + 0) * CH + mycol];
  }

  for (int t = 0; t < CL; ++t) {
    f32x4 vh = {};
    if (t > 0) {
      const unsigned roff = (t & 1) ? (unsigned)(CB * CH * 2) : 0u;
      f32x4 a0 = {}, a1 = {};               // two chains to break MFMA dep latency
#pragma unroll
      for (int kc = 0; kc < 32; kc += 2) {
        auto r0 = __builtin_amdgcn_raw_buffer_load_b128(
            hsrd, (int)(roff + aBase + kc * 64), 0, 17);
        auto r1 = __builtin_amdgcn_raw_buffer_load_b128(
            hsrd, (int)(roff + aBase + kc * 64 + 64), 0, 17);
        a0 = mfma_bf16(__builtin_bit_cast(s16x8, r0), breg[kc],     a0);
        a1 = mfma_bf16(__builtin_bit_cast(s16x8, r1), breg[kc + 1], a1);
      }
      vh = a0 + a1;
    }

    // pointwise (no stores yet)
    float hnv[4]; unsigned short hbv[4];
#pragma unroll
    for (int rr = 0; rr < 4; ++rr) {
      const float u = bf2f(uxr[rr]);
      const float v = vh[rr];
      const float mm = al * (v * u) + b1 * v + b2 * u + bi;
      hnv[rr] = fast_tanh(mm);
      hbv[rr] = f2bf(hnv[rr]);
    }

    if (t < CL - 1) {
      const int tn = t + 1;
      unsigned short* hnext = hping + (size_t)(tn & 1) * (CB * CH);
      // ONLY the 4 h-exchange stores go before the drain
#pragma unroll
      for (int rr = 0; rr < 4; ++rr) {
        const int b = b0 + lg * 4 + rr;
        __hip_atomic_store(hnext + b * CH + mycol, hbv[rr],
                           __ATOMIC_RELAXED, __HIP_MEMORY_SCOPE_SYSTEM);
      }
      asm volatile("s_waitcnt vmcnt(0)" ::: "memory");   // drain = 4 sc0sc1 stores only
      __syncthreads();                                   // all 4 waves drained
      if (tid == 0)
        __hip_atomic_store(&gflags[cs], tn, __ATOMIC_RELAXED, __HIP_MEMORY_SCOPE_SYSTEM);
      // overlap with poll latency: hs stores + next-step ux prefetch
      unsigned short uxn[4];
#pragma unroll
      for (int rr = 0; rr < 4; ++rr) {
        const int b = b0 + lg * 4 + rr;
        hs[((size_t)b * CL + t) * CH + mycol] = hbv[rr];
        uxn[rr] = ux[((size_t)b * CL + tn) * CH + mycol];
      }
      if (wave == 0) {                      // single polling wave per wg
        bool ok;
        do {
          int fv = (lane < 16)
                       ? __hip_atomic_load(&gflags[lane], __ATOMIC_RELAXED,
                                           __HIP_MEMORY_SCOPE_SYSTEM)
                       : tn;
          ok = __all(fv >= tn) != 0;
          if (!ok) __builtin_amdgcn_s_sleep(2);
        } while (!ok);
      }
      __syncthreads();                      // release waves 1-3 after poll
      asm volatile("" ::: "memory");        // no hoisting of h loads above this
#pragma unroll
      for (int rr = 0; rr < 4; ++rr) uxr[rr] = uxn[rr];
    } else {
      // last step: no exchange, no barrier — just final outputs
#pragma unroll
      for (int rr = 0; rr < 4; ++rr) {
        const int b = b0 + lg * 4 + rr;
        hs[((size_t)b * CL + t) * CH + mycol] = hbv[rr];
        out[LOGN + (size_t)b * CH + mycol] = hnv[rr];
      }
    }
  }
}

extern "C" void kernel_launch(void* const* d_in, const int* in_sizes, int n_in,
                              void* d_out, int out_size, void* d_ws, size_t ws_size,
                              hipStream_t stream) {
  const int*   x     = (const int*)  d_in[0];
  const float* emb   = (const float*)d_in[1];
  const float* Uw    = (const float*)d_in[2];
  const float* Vw    = (const float*)d_in[3];
  const float* alpha = (const float*)d_in[4];
  const float* beta1 = (const float*)d_in[5];
  const float* beta2 = (const float*)d_in[6];
  const float* bias  = (const float*)d_in[7];
  const float* decw  = (const float*)d_in[8];
  const float* decb  = (const float*)d_in[9];
  float* out = (float*)d_out;
  char*  ws  = (char*)d_ws;

  int*            flags = (int*)(ws + WS_BAR);
  unsigned short* hping = (unsigned short*)(ws + WS_H);
  unsigned short* embb  = (unsigned short*)(ws + WS_EMBB);
  unsigned short* uwb   = (unsigned short*)(ws + WS_UWB);
  unsigned short* vwb   = (unsigned short*)(ws + WS_VWB);
  unsigned short* dwb   = (unsigned short*)(ws + WS_DECWB);
  unsigned short* uxb   = (unsigned short*)(ws + WS_UX);
  unsigned short* hsb   = (unsigned short*)(ws + WS_HS);

  (void)hipMemsetAsync(ws + WS_BAR, 0, 4096, stream);   // reset flags every call

  k_convert<<<1920, 256, 0, stream>>>(emb, Uw, Vw, decw, embb, uwb, vwb, dwb);

  k_gemm<CE, CH, true, false><<<dim3(CBL / 64, CH / 64), 256, 0, stream>>>(
      embb, x, uwb, nullptr, uxb, nullptr);

  k_rec<<<64, 256, 0, stream>>>(vwb, uxb, hping, hsb, alpha, beta1, beta2, bias, out, flags);

  k_gemm<CH, CV, false, true><<<dim3(CBL / 64, CV / 64), 256, 0, stream>>>(
      hsb, nullptr, dwb, decb, nullptr, out);
}

// Round 6
// 1599.377 us; speedup vs baseline: 9.9828x; 2.2665x over previous
//
#include <hip/hip_runtime.h>

#define DI __device__ __forceinline__

typedef short s16x8 __attribute__((ext_vector_type(8)));
typedef float f32x4 __attribute__((ext_vector_type(4)));

constexpr int CB = 64, CL = 512, CV = 256, CE = 512, CH = 1024;
constexpr int CBL = CB * CL;                // 32768
constexpr size_t LOGN = (size_t)CBL * CV;   // 8388608 floats of logits

// ---- workspace layout (bytes) ----
constexpr size_t WS_BAR   = 0;                              // flags: 4 groups x 64 ints
constexpr size_t WS_H     = 4096;                           // h ping-pong 2*64*1024*2 = 256 KiB
constexpr size_t WS_EMBB  = WS_H    + 2u*CB*CH*2;           // emb bf16   256*512*2
constexpr size_t WS_UWB   = WS_EMBB + (size_t)CV*CE*2;      // U_w bf16   1024*512*2
constexpr size_t WS_VWB   = WS_UWB  + (size_t)CH*CE*2;      // V_w bf16   1024*1024*2
constexpr size_t WS_DECWB = WS_VWB  + (size_t)CH*CH*2;      // dec_w bf16 256*1024*2
constexpr size_t WS_UX    = WS_DECWB+ (size_t)CV*CH*2;      // Ux bf16    32768*1024*2
constexpr size_t WS_HS    = WS_UX   + (size_t)CBL*CH*2;     // hs bf16    32768*1024*2

DI unsigned short f2bf(float f) {            // RNE f32 -> bf16
  unsigned u = __float_as_uint(f);
  u += 0x7FFFu + ((u >> 16) & 1u);
  return (unsigned short)(u >> 16);
}
DI float bf2f(unsigned short h) { return __uint_as_float(((unsigned)h) << 16); }

DI f32x4 mfma_bf16(s16x8 a, s16x8 b, f32x4 c) {
  return __builtin_amdgcn_mfma_f32_16x16x32_bf16(a, b, c, 0, 0, 0);
}

DI float fast_tanh(float x) {
  float a = fminf(fabsf(x), 20.0f);
  float e = __expf(-2.0f * a);
  float r = (1.0f - e) / (1.0f + e);
  return __builtin_copysignf(r, x);
}

// ---------------- convert f32 weights -> bf16 in ws ----------------
__global__ __launch_bounds__(256) void k_convert(
    const float* __restrict__ emb, const float* __restrict__ uw,
    const float* __restrict__ vw,  const float* __restrict__ dw,
    unsigned short* __restrict__ embb, unsigned short* __restrict__ uwb,
    unsigned short* __restrict__ vwb,  unsigned short* __restrict__ dwb)
{
  int i = (blockIdx.x * 256 + threadIdx.x) * 4;   // 1966080 elems total, grid exact
  const float* s; unsigned short* d; int off;
  if      (i < 131072)  { s = emb; d = embb; off = i; }
  else if (i < 655360)  { s = uw;  d = uwb;  off = i - 131072; }
  else if (i < 1703936) { s = vw;  d = vwb;  off = i - 655360; }
  else                  { s = dw;  d = dwb;  off = i - 1703936; }
  float4 v = *(const float4*)(s + off);
  ushort4 o; o.x = f2bf(v.x); o.y = f2bf(v.y); o.z = f2bf(v.z); o.w = f2bf(v.w);
  *(ushort4*)(d + off) = o;
}

// ---------------- generic bf16 MFMA GEMM: C[r, n] = sum_k A[r,k]*B[n,k] ----------------
template<int KD, int NT, bool GATHER, bool OUTF32>
__global__ __launch_bounds__(256) void k_gemm(
    const unsigned short* __restrict__ Asrc,
    const int* __restrict__ xidx,
    const unsigned short* __restrict__ Bsrc,
    const float* __restrict__ biasv,
    unsigned short* __restrict__ Cb,
    float* __restrict__ Cf)
{
  __shared__ unsigned char As[64 * 128];
  __shared__ unsigned char Bs[64 * 128];
  __shared__ int xs[64];

  const int tid = threadIdx.x;
  const int rt = blockIdx.x, ct = blockIdx.y;
  const int r0 = rt * 64, c0 = ct * 64;

  if (GATHER) {
    if (tid < 64) xs[tid] = xidx[r0 + tid];
    __syncthreads();
  }

  const int r  = tid >> 2, kq = tid & 3;
  const unsigned short* aRow = GATHER ? (Asrc + (size_t)xs[r] * KD)
                                      : (Asrc + (size_t)(r0 + r) * KD);
  const unsigned short* bRow = Bsrc + (size_t)(c0 + r) * KD;
  const int dstOff = r * 128 + ((kq * 16) ^ ((r & 7) << 4));

  const int wave = tid >> 6, lane = tid & 63;
  const int ln15 = lane & 15, lg = lane >> 4;
  const int xr = (lane & 7) << 4;
  int aOff[4];
#pragma unroll
  for (int m = 0; m < 4; ++m) aOff[m] = (m * 16 + ln15) * 128 + ((lg * 16) ^ xr);
  const int bOff = (wave * 16 + ln15) * 128 + ((lg * 16) ^ xr);

  f32x4 acc[4] = {};
  for (int kk = 0; kk < KD / 32; ++kk) {
    s16x8 av = *(const s16x8*)(aRow + kk * 32 + kq * 8);
    s16x8 bv = *(const s16x8*)(bRow + kk * 32 + kq * 8);
    __syncthreads();
    *(s16x8*)(As + dstOff) = av;
    *(s16x8*)(Bs + dstOff) = bv;
    __syncthreads();
    s16x8 bf = *(const s16x8*)(Bs + bOff);
#pragma unroll
    for (int m = 0; m < 4; ++m) {
      s16x8 af = *(const s16x8*)(As + aOff[m]);
      acc[m] = mfma_bf16(af, bf, acc[m]);
    }
  }

  const int colg = c0 + wave * 16 + ln15;
  float bv = 0.f;
  if (OUTF32) bv = biasv[colg];
#pragma unroll
  for (int m = 0; m < 4; ++m) {
#pragma unroll
    for (int rr = 0; rr < 4; ++rr) {
      int rowg = r0 + m * 16 + lg * 4 + rr;
      if (OUTF32) Cf[(size_t)rowg * NT + colg] = acc[m][rr] + bv;
      else        Cb[(size_t)rowg * NT + colg] = f2bf(acc[m][rr]);
    }
  }
}

// ---------------- persistent recurrence, v5 ----------------
// 64 wgs x 256 thr. wg=(bg,cs): batches bg*16..+16, cols cs*64..+64.
// v5: (1) V_w slice PINNED in 128 VGPRs (asm keep-alive blocks the compiler's
// remat-in-loop, which had been re-streaming 32 KB/wave/step from L2 —
// VGPR_Count 100 < 128 in R3/R4 was the tell). (2) Cooperative h staging:
// the group's h-slice (16 batches x 1024 = 32 KB, contiguous) is loaded once
// per wg (sc0sc1) into XOR-swizzled LDS; fragments come from ds_read_b128.
// Sync protocol unchanged (proven R2-R4): vmcnt drain -> flag -> wave0 poll.
__global__ __launch_bounds__(256, 1) void k_rec(
    const unsigned short* __restrict__ vwb,   // [H][H] bf16
    const unsigned short* __restrict__ ux,    // [B][L][H] bf16
    unsigned short* __restrict__ hping,       // [2][B][H] bf16
    unsigned short* __restrict__ hs,          // [B][L][H] bf16
    const float* __restrict__ alpha, const float* __restrict__ beta1,
    const float* __restrict__ beta2, const float* __restrict__ bias,
    float* __restrict__ out, int* flags)
{
  __shared__ __align__(16) unsigned char hlds[16 * 2048];   // 32 KiB h-slice

  const int w = blockIdx.x;
  const int bg = w >> 4, cs = w & 15;       // batch-group, col-slice
  const int tid = threadIdx.x;
  const int wave = tid >> 6, lane = tid & 63;
  const int ln15 = lane & 15, lg = lane >> 4;
  const int b0 = bg * 16;
  const int mycol = cs * 64 + wave * 16 + ln15;

  // B-operand resident: breg[kc] lane l = V_w[mycol][kc*32 + (l>>4)*8 ..+8]
  s16x8 breg[32];
  {
    const unsigned short* vrow = vwb + (size_t)mycol * CH + lg * 8;
#pragma unroll
    for (int kc = 0; kc < 32; ++kc) breg[kc] = *(const s16x8*)(vrow + kc * 32);
  }
  // Pin: opaque asm makes values non-rematerializable -> allocator must keep
  // them in VGPRs for the whole kernel (expect VGPR_Count ~200).
#pragma unroll
  for (int kc = 0; kc < 32; ++kc) asm volatile("" : "+v"(breg[kc]));

  const float al = alpha[mycol], b1 = beta1[mycol], b2 = beta2[mycol], bi = bias[mycol];

  // h loads: aux=17 (SC0|SC1) — bypass L1/L2, coherent at L3. Proven R2-R4.
  __amdgpu_buffer_rsrc_t hsrd = __builtin_amdgcn_make_buffer_rsrc(
      (void*)hping, (short)0, (int)(2u * CB * CH * 2), 0x00020000);

  int* gflags = flags + bg * 64;            // one 64B line per group

  // staging: thread stages 8 x 16B; linear offset L = i*4096 + tid*16
  // LDS layout: row (batch) stride 2048B, col swizzle col^((row&7)<<4)
  int sRow[8], sCol[8];
#pragma unroll
  for (int i = 0; i < 8; ++i) {
    const int L = i * 4096 + tid * 16;
    sRow[i] = L >> 11;
    sCol[i] = (L & 2047) ^ ((sRow[i] & 7) << 4);
  }
  const unsigned stgBase = (unsigned)(b0 * 2048);   // byte offset of slice in h buffer

  // fragment read offsets: row ln15, k-chunk lg*8 + kc*32 (bf16) -> bytes
  const int fBase = ln15 * 2048;
  const int fXor  = (ln15 & 7) << 4;

  unsigned short uxr[4];
#pragma unroll
  for (int rr = 0; rr < 4; ++rr) {
    int b = b0 + lg * 4 + rr;
    uxr[rr] = ux[((size_t)b * CL + 0) * CH + mycol];
  }

  for (int t = 0; t < CL; ++t) {
    f32x4 vh = {};
    if (t > 0) {
      // ---- cooperative staging of h(t-1) slice into LDS ----
      const unsigned roff = stgBase + ((t & 1) ? (unsigned)(CB * CH * 2) : 0u);
      s16x8 stg[8];
#pragma unroll
      for (int i = 0; i < 8; ++i) {
        auto raw = __builtin_amdgcn_raw_buffer_load_b128(
            hsrd, (int)(roff + i * 4096 + tid * 16), 0, 17);
        stg[i] = __builtin_bit_cast(s16x8, raw);
      }
#pragma unroll
      for (int i = 0; i < 8; ++i)
        *(s16x8*)(hlds + sRow[i] * 2048 + sCol[i]) = stg[i];
      __syncthreads();                      // LDS h-slice ready for all waves

      // ---- fragments from LDS + MFMA (2 chains) ----
      f32x4 a0 = {}, a1 = {};
#pragma unroll
      for (int kc = 0; kc < 32; kc += 2) {
        s16x8 f0 = *(const s16x8*)(hlds + fBase + ((lg * 16 + kc * 64) ^ fXor));
        s16x8 f1 = *(const s16x8*)(hlds + fBase + ((lg * 16 + kc * 64 + 64) ^ fXor));
        a0 = mfma_bf16(f0, breg[kc],     a0);
        a1 = mfma_bf16(f1, breg[kc + 1], a1);
      }
      vh = a0 + a1;
    }

    // pointwise
    float hnv[4]; unsigned short hbv[4];
#pragma unroll
    for (int rr = 0; rr < 4; ++rr) {
      const float u = bf2f(uxr[rr]);
      const float v = vh[rr];
      const float mm = al * (v * u) + b1 * v + b2 * u + bi;
      hnv[rr] = fast_tanh(mm);
      hbv[rr] = f2bf(hnv[rr]);
    }

    if (t < CL - 1) {
      const int tn = t + 1;
      unsigned short* hnext = hping + (size_t)(tn & 1) * (CB * CH);
      // ONLY the 4 h-exchange stores go before the drain
#pragma unroll
      for (int rr = 0; rr < 4; ++rr) {
        const int b = b0 + lg * 4 + rr;
        __hip_atomic_store(hnext + b * CH + mycol, hbv[rr],
                           __ATOMIC_RELAXED, __HIP_MEMORY_SCOPE_SYSTEM);
      }
      asm volatile("s_waitcnt vmcnt(0)" ::: "memory");   // drain exchange stores
      __syncthreads();                                   // all 4 waves drained
      if (tid == 0)
        __hip_atomic_store(&gflags[cs], tn, __ATOMIC_RELAXED, __HIP_MEMORY_SCOPE_SYSTEM);
      // overlap with poll latency: hs stores + next-step ux prefetch
      unsigned short uxn[4];
#pragma unroll
      for (int rr = 0; rr < 4; ++rr) {
        const int b = b0 + lg * 4 + rr;
        hs[((size_t)b * CL + t) * CH + mycol] = hbv[rr];
        uxn[rr] = ux[((size_t)b * CL + tn) * CH + mycol];
      }
      if (wave == 0) {                      // single polling wave per wg
        bool ok;
        do {
          int fv = (lane < 16)
                       ? __hip_atomic_load(&gflags[lane], __ATOMIC_RELAXED,
                                           __HIP_MEMORY_SCOPE_SYSTEM)
                       : tn;
          ok = __all(fv >= tn) != 0;
          if (!ok) __builtin_amdgcn_s_sleep(1);
        } while (!ok);
      }
      __syncthreads();                      // release all waves; h(t) globally ready
      asm volatile("" ::: "memory");
#pragma unroll
      for (int rr = 0; rr < 4; ++rr) uxr[rr] = uxn[rr];
    } else {
      // last step: no exchange, no barrier — just final outputs
#pragma unroll
      for (int rr = 0; rr < 4; ++rr) {
        const int b = b0 + lg * 4 + rr;
        hs[((size_t)b * CL + t) * CH + mycol] = hbv[rr];
        out[LOGN + (size_t)b * CH + mycol] = hnv[rr];
      }
    }
  }
}

extern "C" void kernel_launch(void* const* d_in, const int* in_sizes, int n_in,
                              void* d_out, int out_size, void* d_ws, size_t ws_size,
                              hipStream_t stream) {
  const int*   x     = (const int*)  d_in[0];
  const float* emb   = (const float*)d_in[1];
  const float* Uw    = (const float*)d_in[2];
  const float* Vw    = (const float*)d_in[3];
  const float* alpha = (const float*)d_in[4];
  const float* beta1 = (const float*)d_in[5];
  const float* beta2 = (const float*)d_in[6];
  const float* bias  = (const float*)d_in[7];
  const float* decw  = (const float*)d_in[8];
  const float* decb  = (const float*)d_in[9];
  float* out = (float*)d_out;
  char*  ws  = (char*)d_ws;

  int*            flags = (int*)(ws + WS_BAR);
  unsigned short* hping = (unsigned short*)(ws + WS_H);
  unsigned short* embb  = (unsigned short*)(ws + WS_EMBB);
  unsigned short* uwb   = (unsigned short*)(ws + WS_UWB);
  unsigned short* vwb   = (unsigned short*)(ws + WS_VWB);
  unsigned short* dwb   = (unsigned short*)(ws + WS_DECWB);
  unsigned short* uxb   = (unsigned short*)(ws + WS_UX);
  unsigned short* hsb   = (unsigned short*)(ws + WS_HS);

  (void)hipMemsetAsync(ws + WS_BAR, 0, 4096, stream);   // reset flags every call

  k_convert<<<1920, 256, 0, stream>>>(emb, Uw, Vw, decw, embb, uwb, vwb, dwb);

  k_gemm<CE, CH, true, false><<<dim3(CBL / 64, CH / 64), 256, 0, stream>>>(
      embb, x, uwb, nullptr, uxb, nullptr);

  k_rec<<<64, 256, 0, stream>>>(vwb, uxb, hping, hsb, alpha, beta1, beta2, bias, out, flags);

  k_gemm<CH, CV, false, true><<<dim3(CBL / 64, CV / 64), 256, 0, stream>>>(
      hsb, nullptr, dwb, decb, nullptr, out);
}

// Round 7
// 1557.483 us; speedup vs baseline: 10.2513x; 1.0269x over previous
//
#include <hip/hip_runtime.h>

#define DI __device__ __forceinline__

typedef short s16x8 __attribute__((ext_vector_type(8)));
typedef float f32x4 __attribute__((ext_vector_type(4)));

constexpr int CB = 64, CL = 512, CV = 256, CE = 512, CH = 1024;
constexpr int CBL = CB * CL;                // 32768
constexpr size_t LOGN = (size_t)CBL * CV;   // 8388608 floats of logits

// ---- workspace layout (bytes) ----
constexpr size_t WS_BAR   = 0;                              // flags: 4 groups x 64 ints
constexpr size_t WS_H     = 4096;                           // h ping-pong 2*64*1024*2 = 256 KiB
constexpr size_t WS_EMBB  = WS_H    + 2u*CB*CH*2;           // emb bf16   256*512*2
constexpr size_t WS_UWB   = WS_EMBB + (size_t)CV*CE*2;      // U_w bf16   1024*512*2
constexpr size_t WS_VWB   = WS_UWB  + (size_t)CH*CE*2;      // V_w bf16   1024*1024*2
constexpr size_t WS_DECWB = WS_VWB  + (size_t)CH*CH*2;      // dec_w bf16 256*1024*2
constexpr size_t WS_UX    = WS_DECWB+ (size_t)CV*CH*2;      // Ux bf16    32768*1024*2
constexpr size_t WS_HS    = WS_UX   + (size_t)CBL*CH*2;     // hs bf16    32768*1024*2

DI unsigned short f2bf(float f) {            // RNE f32 -> bf16
  unsigned u = __float_as_uint(f);
  u += 0x7FFFu + ((u >> 16) & 1u);
  return (unsigned short)(u >> 16);
}
DI float bf2f(unsigned short h) { return __uint_as_float(((unsigned)h) << 16); }

DI f32x4 mfma_bf16(s16x8 a, s16x8 b, f32x4 c) {
  return __builtin_amdgcn_mfma_f32_16x16x32_bf16(a, b, c, 0, 0, 0);
}

DI float fast_tanh(float x) {
  float a = fminf(fabsf(x), 20.0f);
  float e = __expf(-2.0f * a);
  float r = (1.0f - e) / (1.0f + e);
  return __builtin_copysignf(r, x);
}

// ---------------- convert f32 weights -> bf16 in ws ----------------
__global__ __launch_bounds__(256) void k_convert(
    const float* __restrict__ emb, const float* __restrict__ uw,
    const float* __restrict__ vw,  const float* __restrict__ dw,
    unsigned short* __restrict__ embb, unsigned short* __restrict__ uwb,
    unsigned short* __restrict__ vwb,  unsigned short* __restrict__ dwb)
{
  int i = (blockIdx.x * 256 + threadIdx.x) * 4;   // 1966080 elems total, grid exact
  const float* s; unsigned short* d; int off;
  if      (i < 131072)  { s = emb; d = embb; off = i; }
  else if (i < 655360)  { s = uw;  d = uwb;  off = i - 131072; }
  else if (i < 1703936) { s = vw;  d = vwb;  off = i - 655360; }
  else                  { s = dw;  d = dwb;  off = i - 1703936; }
  float4 v = *(const float4*)(s + off);
  ushort4 o; o.x = f2bf(v.x); o.y = f2bf(v.y); o.z = f2bf(v.z); o.w = f2bf(v.w);
  *(ushort4*)(d + off) = o;
}

// ---------------- generic bf16 MFMA GEMM: C[r, n] = sum_k A[r,k]*B[n,k] ----------------
template<int KD, int NT, bool GATHER, bool OUTF32>
__global__ __launch_bounds__(256) void k_gemm(
    const unsigned short* __restrict__ Asrc,
    const int* __restrict__ xidx,
    const unsigned short* __restrict__ Bsrc,
    const float* __restrict__ biasv,
    unsigned short* __restrict__ Cb,
    float* __restrict__ Cf)
{
  __shared__ unsigned char As[64 * 128];
  __shared__ unsigned char Bs[64 * 128];
  __shared__ int xs[64];

  const int tid = threadIdx.x;
  const int rt = blockIdx.x, ct = blockIdx.y;
  const int r0 = rt * 64, c0 = ct * 64;

  if (GATHER) {
    if (tid < 64) xs[tid] = xidx[r0 + tid];
    __syncthreads();
  }

  const int r  = tid >> 2, kq = tid & 3;
  const unsigned short* aRow = GATHER ? (Asrc + (size_t)xs[r] * KD)
                                      : (Asrc + (size_t)(r0 + r) * KD);
  const unsigned short* bRow = Bsrc + (size_t)(c0 + r) * KD;
  const int dstOff = r * 128 + ((kq * 16) ^ ((r & 7) << 4));

  const int wave = tid >> 6, lane = tid & 63;
  const int ln15 = lane & 15, lg = lane >> 4;
  const int xr = (lane & 7) << 4;
  int aOff[4];
#pragma unroll
  for (int m = 0; m < 4; ++m) aOff[m] = (m * 16 + ln15) * 128 + ((lg * 16) ^ xr);
  const int bOff = (wave * 16 + ln15) * 128 + ((lg * 16) ^ xr);

  f32x4 acc[4] = {};
  for (int kk = 0; kk < KD / 32; ++kk) {
    s16x8 av = *(const s16x8*)(aRow + kk * 32 + kq * 8);
    s16x8 bv = *(const s16x8*)(bRow + kk * 32 + kq * 8);
    __syncthreads();
    *(s16x8*)(As + dstOff) = av;
    *(s16x8*)(Bs + dstOff) = bv;
    __syncthreads();
    s16x8 bf = *(const s16x8*)(Bs + bOff);
#pragma unroll
    for (int m = 0; m < 4; ++m) {
      s16x8 af = *(const s16x8*)(As + aOff[m]);
      acc[m] = mfma_bf16(af, bf, acc[m]);
    }
  }

  const int colg = c0 + wave * 16 + ln15;
  float bv = 0.f;
  if (OUTF32) bv = biasv[colg];
#pragma unroll
  for (int m = 0; m < 4; ++m) {
#pragma unroll
    for (int rr = 0; rr < 4; ++rr) {
      int rowg = r0 + m * 16 + lg * 4 + rr;
      if (OUTF32) Cf[(size_t)rowg * NT + colg] = acc[m][rr] + bv;
      else        Cb[(size_t)rowg * NT + colg] = f2bf(acc[m][rr]);
    }
  }
}

// ---------------- persistent recurrence, v6 ----------------
// 64 wgs x 256 thr. wg=(bg,cs): batches bg*16..+16, cols cs*64..+64.
// V_w slice pinned in 128 VGPRs/wave; h exchange sc0sc1 (L3-coherent), no fences.
// v6: decentralized per-producer sync. Staging thread tid's 8 chunks all come
// from producer p=(tid>>3)&15, so each thread polls ONLY flag[p] then loads —
// 16 independent producer->consumer chains; the slowest-producer join folds
// into the LDS syncthreads. hs stores + ux prefetch issue strictly AFTER the
// flag store (overlap next poll), never inside a drained window.
__global__ __launch_bounds__(256, 1) void k_rec(
    const unsigned short* __restrict__ vwb,   // [H][H] bf16
    const unsigned short* __restrict__ ux,    // [B][L][H] bf16
    unsigned short* __restrict__ hping,       // [2][B][H] bf16
    unsigned short* __restrict__ hs,          // [B][L][H] bf16
    const float* __restrict__ alpha, const float* __restrict__ beta1,
    const float* __restrict__ beta2, const float* __restrict__ bias,
    float* __restrict__ out, int* flags)
{
  __shared__ __align__(16) unsigned char hlds[16 * 2048];   // 32 KiB h-slice

  const int w = blockIdx.x;
  const int bg = w >> 4, cs = w & 15;       // batch-group, col-slice
  const int tid = threadIdx.x;
  const int wave = tid >> 6, lane = tid & 63;
  const int ln15 = lane & 15, lg = lane >> 4;
  const int b0 = bg * 16;
  const int mycol = cs * 64 + wave * 16 + ln15;

  // B-operand resident: breg[kc] lane l = V_w[mycol][kc*32 + (l>>4)*8 ..+8]
  s16x8 breg[32];
  {
    const unsigned short* vrow = vwb + (size_t)mycol * CH + lg * 8;
#pragma unroll
    for (int kc = 0; kc < 32; ++kc) breg[kc] = *(const s16x8*)(vrow + kc * 32);
  }
  // Pin: opaque asm blocks remat-in-loop (compiler otherwise re-streams V_w
  // from L2 every step — R5's 2.4x win).
#pragma unroll
  for (int kc = 0; kc < 32; ++kc) asm volatile("" : "+v"(breg[kc]));

  const float al = alpha[mycol], b1 = beta1[mycol], b2 = beta2[mycol], bi = bias[mycol];

  // h loads: aux=17 (SC0|SC1) — bypass L1/L2, coherent at L3. Proven R2-R5.
  __amdgpu_buffer_rsrc_t hsrd = __builtin_amdgcn_make_buffer_rsrc(
      (void*)hping, (short)0, (int)(2u * CB * CH * 2), 0x00020000);

  int* gflags = flags + bg * 64;            // one 64B line per group
  const int myprod = (tid >> 3) & 15;       // ALL 8 of this thread's staged
                                            // chunks come from producer myprod

  // staging: thread stages 8 x 16B; linear offset L = i*4096 + tid*16
  // LDS layout: row (batch) stride 2048B, col swizzle col^((row&7)<<4)
  int sRow[8], sCol[8];
#pragma unroll
  for (int i = 0; i < 8; ++i) {
    const int L = i * 4096 + tid * 16;
    sRow[i] = L >> 11;
    sCol[i] = (L & 2047) ^ ((sRow[i] & 7) << 4);
  }
  const unsigned stgBase = (unsigned)(b0 * 2048);   // byte offset of slice in h buffer

  // fragment read offsets: row ln15, k-chunk lg*8 + kc*32 (bf16) -> bytes
  const int fBase = ln15 * 2048;
  const int fXor  = (ln15 & 7) << 4;

  unsigned short uxr[4];
#pragma unroll
  for (int rr = 0; rr < 4; ++rr) {
    int b = b0 + lg * 4 + rr;
    uxr[rr] = ux[((size_t)b * CL + 0) * CH + mycol];
  }

  for (int t = 0; t < CL; ++t) {
    f32x4 vh = {};
    if (t > 0) {
      // ---- per-thread: wait ONLY for my producer, then stage its chunks ----
      while (__hip_atomic_load(&gflags[myprod], __ATOMIC_RELAXED,
                               __HIP_MEMORY_SCOPE_SYSTEM) < t)
        __builtin_amdgcn_s_sleep(1);
      asm volatile("" ::: "memory");        // no hoisting loads above poll

      const unsigned roff = stgBase + ((t & 1) ? (unsigned)(CB * CH * 2) : 0u);
      s16x8 stg[8];
#pragma unroll
      for (int i = 0; i < 8; ++i) {
        auto raw = __builtin_amdgcn_raw_buffer_load_b128(
            hsrd, (int)(roff + i * 4096 + tid * 16), 0, 17);
        stg[i] = __builtin_bit_cast(s16x8, raw);
      }
#pragma unroll
      for (int i = 0; i < 8; ++i)
        *(s16x8*)(hlds + sRow[i] * 2048 + sCol[i]) = stg[i];
      __syncthreads();                      // LDS h-slice ready (joins all producers)

      // ---- fragments from LDS + MFMA (2 chains) ----
      f32x4 a0 = {}, a1 = {};
#pragma unroll
      for (int kc = 0; kc < 32; kc += 2) {
        s16x8 f0 = *(const s16x8*)(hlds + fBase + ((lg * 16 + kc * 64) ^ fXor));
        s16x8 f1 = *(const s16x8*)(hlds + fBase + ((lg * 16 + kc * 64 + 64) ^ fXor));
        a0 = mfma_bf16(f0, breg[kc],     a0);
        a1 = mfma_bf16(f1, breg[kc + 1], a1);
      }
      vh = a0 + a1;
    }

    // pointwise
    float hnv[4]; unsigned short hbv[4];
#pragma unroll
    for (int rr = 0; rr < 4; ++rr) {
      const float u = bf2f(uxr[rr]);
      const float v = vh[rr];
      const float mm = al * (v * u) + b1 * v + b2 * u + bi;
      hnv[rr] = fast_tanh(mm);
      hbv[rr] = f2bf(hnv[rr]);
    }

    if (t < CL - 1) {
      const int tn = t + 1;
      unsigned short* hnext = hping + (size_t)(tn & 1) * (CB * CH);
      // ONLY the 4 h-exchange stores in the drained window
#pragma unroll
      for (int rr = 0; rr < 4; ++rr) {
        const int b = b0 + lg * 4 + rr;
        __hip_atomic_store(hnext + b * CH + mycol, hbv[rr],
                           __ATOMIC_RELAXED, __HIP_MEMORY_SCOPE_SYSTEM);
      }
      asm volatile("s_waitcnt vmcnt(0)" ::: "memory");   // drain exchange stores
      __syncthreads();                                   // all 4 waves drained
      if (tid == 0)
        __hip_atomic_store(&gflags[cs], tn, __ATOMIC_RELAXED, __HIP_MEMORY_SCOPE_SYSTEM);
      // issued AFTER the flag: hs stores + next ux prefetch overlap next poll
      unsigned short uxn[4];
#pragma unroll
      for (int rr = 0; rr < 4; ++rr) {
        const int b = b0 + lg * 4 + rr;
        hs[((size_t)b * CL + t) * CH + mycol] = hbv[rr];
        uxn[rr] = ux[((size_t)b * CL + tn) * CH + mycol];
      }
#pragma unroll
      for (int rr = 0; rr < 4; ++rr) uxr[rr] = uxn[rr];
    } else {
      // last step: no exchange, no barrier — just final outputs
#pragma unroll
      for (int rr = 0; rr < 4; ++rr) {
        const int b = b0 + lg * 4 + rr;
        hs[((size_t)b * CL + t) * CH + mycol] = hbv[rr];
        out[LOGN + (size_t)b * CH + mycol] = hnv[rr];
      }
    }
  }
}

extern "C" void kernel_launch(void* const* d_in, const int* in_sizes, int n_in,
                              void* d_out, int out_size, void* d_ws, size_t ws_size,
                              hipStream_t stream) {
  const int*   x     = (const int*)  d_in[0];
  const float* emb   = (const float*)d_in[1];
  const float* Uw    = (const float*)d_in[2];
  const float* Vw    = (const float*)d_in[3];
  const float* alpha = (const float*)d_in[4];
  const float* beta1 = (const float*)d_in[5];
  const float* beta2 = (const float*)d_in[6];
  const float* bias  = (const float*)d_in[7];
  const float* decw  = (const float*)d_in[8];
  const float* decb  = (const float*)d_in[9];
  float* out = (float*)d_out;
  char*  ws  = (char*)d_ws;

  int*            flags = (int*)(ws + WS_BAR);
  unsigned short* hping = (unsigned short*)(ws + WS_H);
  unsigned short* embb  = (unsigned short*)(ws + WS_EMBB);
  unsigned short* uwb   = (unsigned short*)(ws + WS_UWB);
  unsigned short* vwb   = (unsigned short*)(ws + WS_VWB);
  unsigned short* dwb   = (unsigned short*)(ws + WS_DECWB);
  unsigned short* uxb   = (unsigned short*)(ws + WS_UX);
  unsigned short* hsb   = (unsigned short*)(ws + WS_HS);

  (void)hipMemsetAsync(ws + WS_BAR, 0, 4096, stream);   // reset flags every call

  k_convert<<<1920, 256, 0, stream>>>(emb, Uw, Vw, decw, embb, uwb, vwb, dwb);

  k_gemm<CE, CH, true, false><<<dim3(CBL / 64, CH / 64), 256, 0, stream>>>(
      embb, x, uwb, nullptr, uxb, nullptr);

  k_rec<<<64, 256, 0, stream>>>(vwb, uxb, hping, hsb, alpha, beta1, beta2, bias, out, flags);

  k_gemm<CH, CV, false, true><<<dim3(CBL / 64, CV / 64), 256, 0, stream>>>(
      hsb, nullptr, dwb, decb, nullptr, out);
}